// Round 3
// baseline (686.850 us; speedup 1.0000x reference)
//
#include <hip/hip_runtime.h>
#include <stdint.h>

#define NU 4096
#define NV 4096
#define DD 256
#define HH 64
#define RR 5

typedef _Float16 f16x8 __attribute__((ext_vector_type(8)));
typedef float f32x4 __attribute__((ext_vector_type(4)));

__device__ __forceinline__ uint16_t f16bits(float f) {
  union { _Float16 h; uint16_t u; } cv;
  cv.h = (_Float16)f;
  return cv.u;
}

// Convert 8 consecutive f32 to f16x8.
__device__ __forceinline__ f16x8 cvt8(const float* p) {
  float4 a = *(const float4*)p;
  float4 b = *(const float4*)(p + 4);
  f16x8 r;
  r[0] = (_Float16)a.x; r[1] = (_Float16)a.y; r[2] = (_Float16)a.z; r[3] = (_Float16)a.w;
  r[4] = (_Float16)b.x; r[5] = (_Float16)b.y; r[6] = (_Float16)b.z; r[7] = (_Float16)b.w;
  return r;
}

// LDS tile layout: 64 rows x 8 k-octets (8 f16 = 16B granules),
// slot(row,koct) = row*8 + (koct ^ (row&7) ^ ((row>>3)&7))  [XOR swizzle: frag
// reads of 16 consecutive rows at fixed koct spread across banks 2-way = free].

// Stage 64x64 f32 tile (row stride gstride f32) -> f16 swizzled LDS tile.
__device__ __forceinline__ void stage_f32(const float* g, char* ldsT, int lane, int gstride) {
  int sub = lane >> 3;  // 0..7
  int s7  = lane & 7;   // 0..7
  f16x8 vals[8];
  #pragma unroll
  for (int c = 0; c < 8; c++)
    vals[c] = cvt8(g + (size_t)(c * 8 + sub) * gstride + s7 * 8);
  #pragma unroll
  for (int c = 0; c < 8; c++) {
    int row = c * 8 + sub;  // row&7==sub, row>>3==c
    int slot = row * 8 + (s7 ^ sub ^ c);
    *(f16x8*)(ldsT + slot * 16) = vals[c];
  }
}

// Stage 64x64 f16 tile (row stride gstride f16) -> swizzled LDS tile.
__device__ __forceinline__ void stage_f16(const _Float16* g, char* ldsT, int lane, int gstride) {
  int sub = lane >> 3;
  int s7  = lane & 7;
  f16x8 vals[8];
  #pragma unroll
  for (int c = 0; c < 8; c++)
    vals[c] = *(const f16x8*)(g + (size_t)(c * 8 + sub) * gstride + s7 * 8);
  #pragma unroll
  for (int c = 0; c < 8; c++) {
    int slot = (c * 8 + sub) * 8 + (s7 ^ sub ^ c);
    *(f16x8*)(ldsT + slot * 16) = vals[c];
  }
}

// Stage transposed: LDS A[m][k=n] = G[k0+n][m0+m] from f32, 64x64, same layout.
// Each lane: 8x8 f32 block (8 n-rows x 8 m-cols), cvt->f16, register transpose.
__device__ __forceinline__ void stage_transpose_f32(const float* g, char* ldsT, int lane, int gstride) {
  int moct = lane & 7;
  int noct = lane >> 3;
  uint16_t hv[8][8];
  #pragma unroll
  for (int j = 0; j < 8; j++) {
    const float* p = g + (size_t)(noct * 8 + j) * gstride + moct * 8;
    float4 a = *(const float4*)p;
    float4 b = *(const float4*)(p + 4);
    hv[j][0] = f16bits(a.x); hv[j][1] = f16bits(a.y); hv[j][2] = f16bits(a.z); hv[j][3] = f16bits(a.w);
    hv[j][4] = f16bits(b.x); hv[j][5] = f16bits(b.y); hv[j][6] = f16bits(b.z); hv[j][7] = f16bits(b.w);
  }
  #pragma unroll
  for (int jm = 0; jm < 8; jm++) {
    uint4 o;
    o.x = (uint32_t)hv[0][jm] | ((uint32_t)hv[1][jm] << 16);
    o.y = (uint32_t)hv[2][jm] | ((uint32_t)hv[3][jm] << 16);
    o.z = (uint32_t)hv[4][jm] | ((uint32_t)hv[5][jm] << 16);
    o.w = (uint32_t)hv[6][jm] | ((uint32_t)hv[7][jm] << 16);
    int m = moct * 8 + jm;
    int slot = m * 8 + (noct ^ (m & 7) ^ ((m >> 3) & 7));
    *(uint4*)(ldsT + slot * 16) = o;
  }
}

// 64x64 output tile, BK=64. A:[row][k] LDS tile, B^T:[h][k] LDS tile.
// A-frag: A[m=lane&15][k=(lane>>4)*8+j]; C/D: col=lane&15, row=(lane>>4)*4+i.
__device__ __forceinline__ void mfma_tile64(const char* ldsA, const char* ldsB,
                                            f32x4 acc[4][4], int lane) {
  int rowl = lane & 15;
  int q = lane >> 4;
  #pragma unroll
  for (int ks = 0; ks < 2; ks++) {
    int koct = ks * 4 + q;
    f16x8 af[4], bfr[4];
    #pragma unroll
    for (int mt = 0; mt < 4; mt++) {
      int row = mt * 16 + rowl;
      int slot = row * 8 + (koct ^ (row & 7) ^ ((row >> 3) & 7));
      af[mt] = *(const f16x8*)(ldsA + slot * 16);
    }
    #pragma unroll
    for (int ht = 0; ht < 4; ht++) {
      int row = ht * 16 + rowl;
      int slot = row * 8 + (koct ^ (row & 7) ^ ((row >> 3) & 7));
      bfr[ht] = *(const f16x8*)(ldsB + slot * 16);
    }
    #pragma unroll
    for (int mt = 0; mt < 4; mt++)
      #pragma unroll
      for (int ht = 0; ht < 4; ht++)
        acc[mt][ht] = __builtin_amdgcn_mfma_f32_16x16x32_f16(af[mt], bfr[ht], acc[mt][ht], 0, 0, 0);
  }
}

// ---------------- Kernel Z: zero the atomic accumulators ----------------
__global__ __launch_bounds__(256) void k_zero(float* __restrict__ p) {
  p[blockIdx.x * 256 + threadIdx.x] = 0.f;  // grid covers sums+Yu+Yv exactly
}

// ---------------- Kernel A: row/col sums of support (f32) ----------------
__global__ __launch_bounds__(256) void k_sums(const float* __restrict__ S,
                                              float* __restrict__ rowsum,
                                              float* __restrict__ colsum) {
  int r = blockIdx.x >> 7;
  int chunk = blockIdx.x & 127;
  int n0 = chunk * 32;
  int t = threadIdx.x;
  const float* base = S + (size_t)r * NU * NV;
  float colacc[16];
  #pragma unroll
  for (int j = 0; j < 16; j++) colacc[j] = 0.f;
  for (int nr = 0; nr < 32; nr++) {
    const float* row = base + (size_t)(n0 + nr) * NV;
    float rp = 0.f;
    #pragma unroll
    for (int j = 0; j < 4; j++) {
      float4 v = *(const float4*)(row + j * 1024 + t * 4);
      rp += v.x + v.y + v.z + v.w;
      colacc[j * 4 + 0] += v.x; colacc[j * 4 + 1] += v.y;
      colacc[j * 4 + 2] += v.z; colacc[j * 4 + 3] += v.w;
    }
    #pragma unroll
    for (int off = 32; off > 0; off >>= 1) rp += __shfl_xor(rp, off, 64);
    if ((t & 63) == 0) atomicAdd(&rowsum[r * NU + n0 + nr], rp);
  }
  #pragma unroll
  for (int j = 0; j < 4; j++)
    #pragma unroll
    for (int i = 0; i < 4; i++)
      atomicAdd(&colsum[r * NV + j * 1024 + t * 4 + i], colacc[j * 4 + i]);
}

// ---------------- Kernel B1: guarded rsqrt ----------------
__global__ __launch_bounds__(256) void k_inv(const float* __restrict__ sums,
                                             float* __restrict__ invs) {
  int i = blockIdx.x * 256 + threadIdx.x;  // 40960 exact
  float v = sums[i];
  invs[i] = v > 0.f ? rsqrtf(v) : 0.f;
}

// ---------------- Kernel B2: weight cumsum + transpose to f16 [r][h][d] ----------------
__global__ __launch_bounds__(256) void k_wt(const float* __restrict__ uw,
                                            const float* __restrict__ vw,
                                            _Float16* __restrict__ wtu,
                                            _Float16* __restrict__ wtv) {
  int r = blockIdx.x % RR;
  const float* w = (blockIdx.x < RR) ? uw : vw;
  _Float16* o = (blockIdx.x < RR) ? wtu : wtv;
  int t = threadIdx.x;  // d
  for (int h = 0; h < HH; h++) {
    float s = 0.f;
    for (int rp = 0; rp <= r; rp++) s += w[rp * DD * HH + t * HH + h];
    o[(size_t)(r * HH + h) * DD + t] = (_Float16)s;
  }
}

// ---------------- Kernel C: tmp = feat @ cumW, scaled, stored f16 transposed ----------------
// dir=0: TuT[r][h][n] = c_inv[r,n] * (u_feat @ cum_uw[r])[n,h]
// dir=1: TvT[r][h][m] = r_inv[r,m] * (v_feat @ cum_vw[r])[m,h]
__global__ __launch_bounds__(128) void k_tmp(const float* __restrict__ u_feat,
                                             const float* __restrict__ v_feat,
                                             const _Float16* __restrict__ wtu,
                                             const _Float16* __restrict__ wtv,
                                             const float* __restrict__ invs,
                                             _Float16* __restrict__ TuT,
                                             _Float16* __restrict__ TvT) {
  __shared__ __align__(16) char lds[32768];
  int bx = blockIdx.x, r = blockIdx.y, dir = blockIdx.z;
  int t = threadIdx.x, w = t >> 6, lane = t & 63;
  char* ldsA = lds + w * 16384;
  char* ldsB = ldsA + 8192;
  const float* feat = dir ? v_feat : u_feat;
  const _Float16* wt = dir ? wtv : wtu;
  const float* inv = invs + (dir ? (size_t)RR * NU : 0);
  _Float16* outT = dir ? TvT : TuT;
  int n0 = bx * 64;
  f32x4 acc[4][4];
  #pragma unroll
  for (int a = 0; a < 4; a++)
    #pragma unroll
    for (int b = 0; b < 4; b++) acc[a][b] = (f32x4){0.f, 0.f, 0.f, 0.f};
  #pragma unroll
  for (int cc = 0; cc < 2; cc++) {
    int kw = (w * 2 + cc) * 64;  // wave-private K range
    stage_f32(feat + (size_t)n0 * DD + kw, ldsA, lane, DD);
    stage_f16(wt + (size_t)(r * HH) * DD + kw, ldsB, lane, DD);
    mfma_tile64(ldsA, ldsB, acc, lane);
  }
  {  // wave-private f32 slab over this wave's A+B region
    float* slab = (float*)ldsA;
    int rowl = lane & 15, q = lane >> 4;
    #pragma unroll
    for (int mt = 0; mt < 4; mt++)
      #pragma unroll
      for (int ht = 0; ht < 4; ht++)
        #pragma unroll
        for (int i = 0; i < 4; i++)
          slab[(mt * 16 + q * 4 + i) * 64 + ht * 16 + rowl] = acc[mt][ht][i];
  }
  __syncthreads();
  {
    int h = t & 63, rg = t >> 6;  // rg in {0,1}
    uint32_t pk[16];
    #pragma unroll
    for (int p = 0; p < 16; p++) {
      int rl = rg * 32 + 2 * p;
      float s0 = ((const float*)lds)[rl * 64 + h] + ((const float*)(lds + 16384))[rl * 64 + h];
      float s1 = ((const float*)lds)[(rl + 1) * 64 + h] + ((const float*)(lds + 16384))[(rl + 1) * 64 + h];
      s0 *= inv[r * NU + n0 + rl];
      s1 *= inv[r * NU + n0 + rl + 1];
      pk[p] = (uint32_t)f16bits(s0) | ((uint32_t)f16bits(s1) << 16);
    }
    uint32_t* ob = (uint32_t*)(outT + ((size_t)(r * HH + h) * NU + n0 + rg * 32));
    #pragma unroll
    for (int p = 0; p < 16; p++) ob[p] = pk[p];
  }
}

// ---------------- Kernel D: big GEMMs, accumulate over r/K-half via atomicAdd ----------------
// dir=0: Yu[n][h] += c_inv[r,n] * sum_k S[r][n][k] * TvT[r][h][k]
// dir=1: Yv[m][h] += r_inv[r,m] * sum_k S[r][k][m] * TuT[r][h][k]
__global__ __launch_bounds__(128) void k_gemm(const float* __restrict__ S,
                                              const _Float16* __restrict__ TuT,
                                              const _Float16* __restrict__ TvT,
                                              const float* __restrict__ invs,
                                              float* __restrict__ Yu,
                                              float* __restrict__ Yv) {
  __shared__ __align__(16) char lds[32768];
  int bx = blockIdx.x, r = blockIdx.y, dir = blockIdx.z;
  int mtile = bx & 63, khalf = bx >> 6;
  int t = threadIdx.x, w = t >> 6, lane = t & 63;
  char* ldsA = lds + w * 16384;
  char* ldsB = ldsA + 8192;
  const float* Sr = S + (size_t)r * NU * NV;
  const _Float16* Tb = (dir ? TuT : TvT) + (size_t)r * HH * NV;
  const float* inv = invs + (dir ? (size_t)RR * NU : 0) + (size_t)r * NU;
  float* Yo = (dir ? Yv : Yu) + (size_t)mtile * 64 * HH;
  int row0 = mtile * 64;
  f32x4 acc[4][4];
  #pragma unroll
  for (int a = 0; a < 4; a++)
    #pragma unroll
    for (int b = 0; b < 4; b++) acc[a][b] = (f32x4){0.f, 0.f, 0.f, 0.f};
  for (int ch = 0; ch < 16; ch++) {
    int k0 = khalf * 2048 + w * 1024 + ch * 64;  // wave-private K range: no barriers
    if (dir == 0) {
      stage_f32(Sr + (size_t)row0 * NV + k0, ldsA, lane, NV);
    } else {
      stage_transpose_f32(Sr + (size_t)k0 * NV + row0, ldsA, lane, NV);
    }
    stage_f16(Tb + k0, ldsB, lane, NV);
    mfma_tile64(ldsA, ldsB, acc, lane);
  }
  {
    float* slab = (float*)ldsA;
    int rowl = lane & 15, q = lane >> 4;
    #pragma unroll
    for (int mt = 0; mt < 4; mt++)
      #pragma unroll
      for (int ht = 0; ht < 4; ht++)
        #pragma unroll
        for (int i = 0; i < 4; i++)
          slab[(mt * 16 + q * 4 + i) * 64 + ht * 16 + rowl] = acc[mt][ht][i];
  }
  __syncthreads();
  {
    int h = t & 63, rg = t >> 6;
    #pragma unroll
    for (int j = 0; j < 32; j++) {
      int row = rg * 32 + j;
      float s = ((const float*)lds)[row * 64 + h] + ((const float*)(lds + 16384))[row * 64 + h];
      atomicAdd(&Yo[(size_t)row * HH + h], s * inv[row0 + row]);
    }
  }
}

// ---------------- Kernel E: gather + bias + relu -> f32 out ----------------
__global__ __launch_bounds__(256) void k_out(const int* __restrict__ u, const int* __restrict__ v,
                                             const float* __restrict__ Yu, const float* __restrict__ Yv,
                                             const float* __restrict__ bias,
                                             float* __restrict__ out) {
  int T = blockIdx.x * 256 + threadIdx.x;  // 262144 float2 = 524288 f32 exact
  int dir = T >> 17;
  int rem = T & 131071;
  int b = rem >> 5;
  int h = (rem & 31) * 2;
  int idx = dir ? v[b] : u[b];
  const float* Y = (dir ? Yv : Yu) + (size_t)idx * HH + h;
  float s0 = Y[0] + bias[h];
  float s1 = Y[1] + bias[h + 1];
  float2 o;
  o.x = s0 > 0.f ? s0 : 0.f;
  o.y = s1 > 0.f ? s1 : 0.f;
  ((float2*)out)[T] = o;
}

extern "C" void kernel_launch(void* const* d_in, const int* in_sizes, int n_in,
                              void* d_out, int out_size, void* d_ws, size_t ws_size,
                              hipStream_t stream) {
  (void)in_sizes; (void)n_in; (void)out_size; (void)ws_size;
  const float* u_feat = (const float*)d_in[0];
  const float* v_feat = (const float*)d_in[1];
  const int* u = (const int*)d_in[2];
  const int* v = (const int*)d_in[3];
  const float* S = (const float*)d_in[4];
  const float* uw = (const float*)d_in[5];
  const float* vw = (const float*)d_in[6];
  const float* bias = (const float*)d_in[7];

  char* ws = (char*)d_ws;
  // [sums 160K][Yu 1M][Yv 1M][invs 160K][wtu 160K][wtv 160K][TuT 2.5M][TvT 2.5M] ~7.6MB
  float* sums = (float*)ws;
  float* Yu   = (float*)(ws + 163840);
  float* Yv   = (float*)(ws + 1212416);
  float* invs = (float*)(ws + 2260992);
  _Float16* wtu = (_Float16*)(ws + 2424832);
  _Float16* wtv = (_Float16*)(ws + 2588672);
  _Float16* TuT = (_Float16*)(ws + 2752512);
  _Float16* TvT = (_Float16*)(ws + 5373952);

  k_zero<<<2208, 256, 0, stream>>>(sums);  // sums+Yu+Yv contiguous: 565248 f32
  k_wt<<<2 * RR, 256, 0, stream>>>(uw, vw, wtu, wtv);
  k_sums<<<RR * 128, 256, 0, stream>>>(S, sums, sums + (size_t)RR * NU);
  k_inv<<<160, 256, 0, stream>>>(sums, invs);
  k_tmp<<<dim3(64, RR, 2), 128, 0, stream>>>(u_feat, v_feat, wtu, wtv, invs, TuT, TvT);
  k_gemm<<<dim3(128, RR, 2), 128, 0, stream>>>(S, TuT, TvT, invs, Yu, Yv);
  k_out<<<1024, 256, 0, stream>>>(u, v, Yu, Yv, bias, (float*)d_out);
}

// Round 4
// 602.220 us; speedup vs baseline: 1.1405x; 1.1405x over previous
//
#include <hip/hip_runtime.h>
#include <stdint.h>

#define NU 4096
#define NV 4096
#define DD 256
#define HH 64
#define RR 5

typedef _Float16 f16x8 __attribute__((ext_vector_type(8)));
typedef _Float16 f16x4 __attribute__((ext_vector_type(4)));
typedef float f32x4 __attribute__((ext_vector_type(4)));

__device__ __forceinline__ uint16_t f16bits(float f) {
  union { _Float16 h; uint16_t u; } cv;
  cv.h = (_Float16)f;
  return cv.u;
}

// Convert 8 consecutive f32 to f16x8.
__device__ __forceinline__ f16x8 cvt8(const float* p) {
  float4 a = *(const float4*)p;
  float4 b = *(const float4*)(p + 4);
  f16x8 r;
  r[0] = (_Float16)a.x; r[1] = (_Float16)a.y; r[2] = (_Float16)a.z; r[3] = (_Float16)a.w;
  r[4] = (_Float16)b.x; r[5] = (_Float16)b.y; r[6] = (_Float16)b.z; r[7] = (_Float16)b.w;
  return r;
}

// LDS tile layout: 64 rows x 8 k-octets (8 f16 = 16B granules),
// slot(row,koct) = row*8 + (koct ^ (row&7) ^ ((row>>3)&7)).

// Stage 64x64 f32 tile (row stride gstride f32) -> f16 swizzled LDS tile.
__device__ __forceinline__ void stage_f32(const float* g, char* ldsT, int lane, int gstride) {
  int sub = lane >> 3;
  int s7  = lane & 7;
  f16x8 vals[8];
  #pragma unroll
  for (int c = 0; c < 8; c++)
    vals[c] = cvt8(g + (size_t)(c * 8 + sub) * gstride + s7 * 8);
  #pragma unroll
  for (int c = 0; c < 8; c++) {
    int row = c * 8 + sub;
    int slot = row * 8 + (s7 ^ sub ^ c);
    *(f16x8*)(ldsT + slot * 16) = vals[c];
  }
}

// Stage 64x64 f16 tile (row stride gstride f16) -> swizzled LDS tile. 8x16B loads.
__device__ __forceinline__ void stage_f16(const _Float16* g, char* ldsT, int lane, int gstride) {
  int sub = lane >> 3;
  int s7  = lane & 7;
  f16x8 vals[8];
  #pragma unroll
  for (int c = 0; c < 8; c++)
    vals[c] = *(const f16x8*)(g + (size_t)(c * 8 + sub) * gstride + s7 * 8);
  #pragma unroll
  for (int c = 0; c < 8; c++) {
    int slot = (c * 8 + sub) * 8 + (s7 ^ sub ^ c);
    *(f16x8*)(ldsT + slot * 16) = vals[c];
  }
}

// Stage transposed from f16: LDS A[m][k=n] = G[k0+n][m0+m], 64x64, same layout.
// Lane: 8x8 f16 block (8 n-rows x 8 m-cols), register transpose, 8x ds_write_b128.
__device__ __forceinline__ void stage_transpose_f16(const _Float16* g, char* ldsT, int lane, int gstride) {
  int moct = lane & 7;
  int noct = lane >> 3;
  uint32_t rw[8][4];
  #pragma unroll
  for (int j = 0; j < 8; j++) {
    uint4 vv = *(const uint4*)(g + (size_t)(noct * 8 + j) * gstride + moct * 8);
    rw[j][0] = vv.x; rw[j][1] = vv.y; rw[j][2] = vv.z; rw[j][3] = vv.w;
  }
  #pragma unroll
  for (int jm = 0; jm < 8; jm++) {
    uint4 o;
    #define XTR(J) ((rw[J][jm >> 1] >> ((jm & 1) * 16)) & 0xFFFFu)
    o.x = XTR(0) | (XTR(1) << 16);
    o.y = XTR(2) | (XTR(3) << 16);
    o.z = XTR(4) | (XTR(5) << 16);
    o.w = XTR(6) | (XTR(7) << 16);
    #undef XTR
    int m = moct * 8 + jm;
    int slot = m * 8 + (noct ^ (m & 7) ^ ((m >> 3) & 7));
    *(uint4*)(ldsT + slot * 16) = o;
  }
}

// 64x64 output tile, BK=64. A:[row][k] LDS tile, B^T:[h][k] LDS tile.
__device__ __forceinline__ void mfma_tile64(const char* ldsA, const char* ldsB,
                                            f32x4 acc[4][4], int lane) {
  int rowl = lane & 15;
  int q = lane >> 4;
  #pragma unroll
  for (int ks = 0; ks < 2; ks++) {
    int koct = ks * 4 + q;
    f16x8 af[4], bfr[4];
    #pragma unroll
    for (int mt = 0; mt < 4; mt++) {
      int row = mt * 16 + rowl;
      int slot = row * 8 + (koct ^ (row & 7) ^ ((row >> 3) & 7));
      af[mt] = *(const f16x8*)(ldsA + slot * 16);
    }
    #pragma unroll
    for (int ht = 0; ht < 4; ht++) {
      int row = ht * 16 + rowl;
      int slot = row * 8 + (koct ^ (row & 7) ^ ((row >> 3) & 7));
      bfr[ht] = *(const f16x8*)(ldsB + slot * 16);
    }
    #pragma unroll
    for (int mt = 0; mt < 4; mt++)
      #pragma unroll
      for (int ht = 0; ht < 4; ht++)
        acc[mt][ht] = __builtin_amdgcn_mfma_f32_16x16x32_f16(af[mt], bfr[ht], acc[mt][ht], 0, 0, 0);
  }
}

// ---------------- Kernel Z: zero the atomic accumulators ----------------
__global__ __launch_bounds__(256) void k_zero(float* __restrict__ p) {
  p[blockIdx.x * 256 + threadIdx.x] = 0.f;
}

// ---------------- Kernel P: fused S f32->f16 convert + row/col sums ----------------
// Sh[r][n][m] = (f16)S[r][n][m]; rowsum[r][n] = sum_m; colsum[r][m] = sum_n.
__global__ __launch_bounds__(256) void k_prep(const float* __restrict__ S,
                                              _Float16* __restrict__ Sh,
                                              float* __restrict__ rowsum,
                                              float* __restrict__ colsum) {
  int r = blockIdx.x >> 7;
  int chunk = blockIdx.x & 127;
  int n0 = chunk * 32;
  int t = threadIdx.x;
  const float* base = S + (size_t)r * NU * NV;
  _Float16* hbase = Sh + (size_t)r * NU * NV;
  float colacc[16];
  #pragma unroll
  for (int j = 0; j < 16; j++) colacc[j] = 0.f;
  for (int nr = 0; nr < 32; nr++) {
    const float* row = base + (size_t)(n0 + nr) * NV;
    _Float16* hrow = hbase + (size_t)(n0 + nr) * NV;
    float rp = 0.f;
    #pragma unroll
    for (int j = 0; j < 4; j++) {
      float4 v = *(const float4*)(row + j * 1024 + t * 4);
      rp += v.x + v.y + v.z + v.w;
      colacc[j * 4 + 0] += v.x; colacc[j * 4 + 1] += v.y;
      colacc[j * 4 + 2] += v.z; colacc[j * 4 + 3] += v.w;
      f16x4 hv;
      hv[0] = (_Float16)v.x; hv[1] = (_Float16)v.y;
      hv[2] = (_Float16)v.z; hv[3] = (_Float16)v.w;
      *(f16x4*)(hrow + j * 1024 + t * 4) = hv;
    }
    #pragma unroll
    for (int off = 32; off > 0; off >>= 1) rp += __shfl_xor(rp, off, 64);
    if ((t & 63) == 0) atomicAdd(&rowsum[r * NU + n0 + nr], rp);
  }
  #pragma unroll
  for (int j = 0; j < 4; j++)
    #pragma unroll
    for (int i = 0; i < 4; i++)
      atomicAdd(&colsum[r * NV + j * 1024 + t * 4 + i], colacc[j * 4 + i]);
}

// ---------------- Kernel B1: guarded rsqrt ----------------
__global__ __launch_bounds__(256) void k_inv(const float* __restrict__ sums,
                                             float* __restrict__ invs) {
  int i = blockIdx.x * 256 + threadIdx.x;  // 40960 exact
  float v = sums[i];
  invs[i] = v > 0.f ? rsqrtf(v) : 0.f;
}

// ---------------- Kernel B2: weight cumsum + transpose to f16 [r][h][d] ----------------
// One thread per (side,r,d,h); coalesced stride-16384 reads.
__global__ __launch_bounds__(256) void k_wt(const float* __restrict__ uw,
                                            const float* __restrict__ vw,
                                            _Float16* __restrict__ wtu,
                                            _Float16* __restrict__ wtv) {
  int r = blockIdx.y, side = blockIdx.z;
  int e = blockIdx.x * 256 + threadIdx.x;  // 64 blocks x: 16384 elements (d*64+h)
  int d = e >> 6, h = e & 63;
  const float* w = side ? vw : uw;
  _Float16* o = side ? wtv : wtu;
  float s = 0.f;
  #pragma unroll
  for (int rp = 0; rp < RR; rp++)
    if (rp <= r) s += w[rp * DD * HH + e];
  o[(size_t)(r * HH + h) * DD + d] = (_Float16)s;
}

// ---------------- Kernel C: tmp = feat @ cumW, scaled, stored f16 transposed ----------------
// dir=0: TuT[r][h][n] = c_inv[r,n] * (u_feat @ cum_uw[r])[n,h]
// dir=1: TvT[r][h][m] = r_inv[r,m] * (v_feat @ cum_vw[r])[m,h]
__global__ __launch_bounds__(128) void k_tmp(const float* __restrict__ u_feat,
                                             const float* __restrict__ v_feat,
                                             const _Float16* __restrict__ wtu,
                                             const _Float16* __restrict__ wtv,
                                             const float* __restrict__ invs,
                                             _Float16* __restrict__ TuT,
                                             _Float16* __restrict__ TvT) {
  __shared__ __align__(16) char lds[32768];
  int bx = blockIdx.x, r = blockIdx.y, dir = blockIdx.z;
  int t = threadIdx.x, w = t >> 6, lane = t & 63;
  char* ldsA = lds + w * 16384;
  char* ldsB = ldsA + 8192;
  const float* feat = dir ? v_feat : u_feat;
  const _Float16* wt = dir ? wtv : wtu;
  const float* inv = invs + (dir ? (size_t)RR * NU : 0);
  _Float16* outT = dir ? TvT : TuT;
  int n0 = bx * 64;
  f32x4 acc[4][4];
  #pragma unroll
  for (int a = 0; a < 4; a++)
    #pragma unroll
    for (int b = 0; b < 4; b++) acc[a][b] = (f32x4){0.f, 0.f, 0.f, 0.f};
  #pragma unroll
  for (int cc = 0; cc < 2; cc++) {
    int kw = (w * 2 + cc) * 64;  // wave-private K range
    stage_f32(feat + (size_t)n0 * DD + kw, ldsA, lane, DD);
    stage_f16(wt + (size_t)(r * HH) * DD + kw, ldsB, lane, DD);
    mfma_tile64(ldsA, ldsB, acc, lane);
  }
  {
    float* slab = (float*)ldsA;
    int rowl = lane & 15, q = lane >> 4;
    #pragma unroll
    for (int mt = 0; mt < 4; mt++)
      #pragma unroll
      for (int ht = 0; ht < 4; ht++)
        #pragma unroll
        for (int i = 0; i < 4; i++)
          slab[(mt * 16 + q * 4 + i) * 64 + ht * 16 + rowl] = acc[mt][ht][i];
  }
  __syncthreads();
  {
    int h = t & 63, rg = t >> 6;
    uint32_t pk[16];
    #pragma unroll
    for (int p = 0; p < 16; p++) {
      int rl = rg * 32 + 2 * p;
      float s0 = ((const float*)lds)[rl * 64 + h] + ((const float*)(lds + 16384))[rl * 64 + h];
      float s1 = ((const float*)lds)[(rl + 1) * 64 + h] + ((const float*)(lds + 16384))[(rl + 1) * 64 + h];
      s0 *= inv[r * NU + n0 + rl];
      s1 *= inv[r * NU + n0 + rl + 1];
      pk[p] = (uint32_t)f16bits(s0) | ((uint32_t)f16bits(s1) << 16);
    }
    uint32_t* ob = (uint32_t*)(outT + ((size_t)(r * HH + h) * NU + n0 + rg * 32));
    #pragma unroll
    for (int p = 0; p < 16; p++) ob[p] = pk[p];
  }
}

// ---------------- Kernel D: big GEMMs over f16 Sh, accumulate via atomicAdd ----------------
// dir=0: Yu[n][h] += c_inv[r,n] * sum_k Sh[r][n][k] * TvT[r][h][k]
// dir=1: Yv[m][h] += r_inv[r,m] * sum_k Sh[r][k][m] * TuT[r][h][k]
__global__ __launch_bounds__(128) void k_gemm(const _Float16* __restrict__ Sh,
                                              const _Float16* __restrict__ TuT,
                                              const _Float16* __restrict__ TvT,
                                              const float* __restrict__ invs,
                                              float* __restrict__ Yu,
                                              float* __restrict__ Yv) {
  __shared__ __align__(16) char lds[32768];
  int bx = blockIdx.x, r = blockIdx.y, dir = blockIdx.z;
  int mtile = bx & 63, khalf = bx >> 6;
  int t = threadIdx.x, w = t >> 6, lane = t & 63;
  char* ldsA = lds + w * 16384;
  char* ldsB = ldsA + 8192;
  const _Float16* Sr = Sh + (size_t)r * NU * NV;
  const _Float16* Tb = (dir ? TuT : TvT) + (size_t)r * HH * NV;
  const float* inv = invs + (dir ? (size_t)RR * NU : 0) + (size_t)r * NU;
  float* Yo = (dir ? Yv : Yu) + (size_t)mtile * 64 * HH;
  int row0 = mtile * 64;
  f32x4 acc[4][4];
  #pragma unroll
  for (int a = 0; a < 4; a++)
    #pragma unroll
    for (int b = 0; b < 4; b++) acc[a][b] = (f32x4){0.f, 0.f, 0.f, 0.f};
  for (int ch = 0; ch < 16; ch++) {
    int k0 = khalf * 2048 + w * 1024 + ch * 64;  // wave-private K range: no barriers
    if (dir == 0) {
      stage_f16(Sr + (size_t)row0 * NV + k0, ldsA, lane, NV);
    } else {
      stage_transpose_f16(Sr + (size_t)k0 * NV + row0, ldsA, lane, NV);
    }
    stage_f16(Tb + k0, ldsB, lane, NV);
    mfma_tile64(ldsA, ldsB, acc, lane);
  }
  {
    float* slab = (float*)ldsA;
    int rowl = lane & 15, q = lane >> 4;
    #pragma unroll
    for (int mt = 0; mt < 4; mt++)
      #pragma unroll
      for (int ht = 0; ht < 4; ht++)
        #pragma unroll
        for (int i = 0; i < 4; i++)
          slab[(mt * 16 + q * 4 + i) * 64 + ht * 16 + rowl] = acc[mt][ht][i];
  }
  __syncthreads();
  {
    int h = t & 63, rg = t >> 6;
    #pragma unroll
    for (int j = 0; j < 32; j++) {
      int row = rg * 32 + j;
      float s = ((const float*)lds)[row * 64 + h] + ((const float*)(lds + 16384))[row * 64 + h];
      atomicAdd(&Yo[(size_t)row * HH + h], s * inv[row0 + row]);
    }
  }
}

// ---------------- Kernel E: gather + bias + relu -> f32 out ----------------
__global__ __launch_bounds__(256) void k_out(const int* __restrict__ u, const int* __restrict__ v,
                                             const float* __restrict__ Yu, const float* __restrict__ Yv,
                                             const float* __restrict__ bias,
                                             float* __restrict__ out) {
  int T = blockIdx.x * 256 + threadIdx.x;
  int dir = T >> 17;
  int rem = T & 131071;
  int b = rem >> 5;
  int h = (rem & 31) * 2;
  int idx = dir ? v[b] : u[b];
  const float* Y = (dir ? Yv : Yu) + (size_t)idx * HH + h;
  float s0 = Y[0] + bias[h];
  float s1 = Y[1] + bias[h + 1];
  float2 o;
  o.x = s0 > 0.f ? s0 : 0.f;
  o.y = s1 > 0.f ? s1 : 0.f;
  ((float2*)out)[T] = o;
}

extern "C" void kernel_launch(void* const* d_in, const int* in_sizes, int n_in,
                              void* d_out, int out_size, void* d_ws, size_t ws_size,
                              hipStream_t stream) {
  (void)in_sizes; (void)n_in; (void)out_size; (void)ws_size;
  const float* u_feat = (const float*)d_in[0];
  const float* v_feat = (const float*)d_in[1];
  const int* u = (const int*)d_in[2];
  const int* v = (const int*)d_in[3];
  const float* S = (const float*)d_in[4];
  const float* uw = (const float*)d_in[5];
  const float* vw = (const float*)d_in[6];
  const float* bias = (const float*)d_in[7];

  char* ws = (char*)d_ws;
  // [sums 160K][Yu 1M][Yv 1M][invs 160K][wtu 160K][wtv 160K][TuT 2.5M][TvT 2.5M][Sh 160M]
  float* sums = (float*)ws;
  float* Yu   = (float*)(ws + 163840);
  float* Yv   = (float*)(ws + 1212416);
  float* invs = (float*)(ws + 2260992);
  _Float16* wtu = (_Float16*)(ws + 2424832);
  _Float16* wtv = (_Float16*)(ws + 2588672);
  _Float16* TuT = (_Float16*)(ws + 2752512);
  _Float16* TvT = (_Float16*)(ws + 5373952);
  _Float16* Sh  = (_Float16*)(ws + 7995392);  // 5*4096*4096*2 = 160 MiB

  k_zero<<<2208, 256, 0, stream>>>(sums);  // sums+Yu+Yv contiguous: 565248 f32
  k_wt<<<dim3(64, RR, 2), 256, 0, stream>>>(uw, vw, wtu, wtv);
  k_prep<<<RR * 128, 256, 0, stream>>>(S, Sh, sums, sums + (size_t)RR * NU);
  k_inv<<<160, 256, 0, stream>>>(sums, invs);
  k_tmp<<<dim3(64, RR, 2), 128, 0, stream>>>(u_feat, v_feat, wtu, wtv, invs, TuT, TvT);
  k_gemm<<<dim3(128, RR, 2), 128, 0, stream>>>(Sh, TuT, TvT, invs, Yu, Yv);
  k_out<<<1024, 256, 0, stream>>>(u, v, Yu, Yv, bias, (float*)d_out);
}